// Round 2
// baseline (607.563 us; speedup 1.0000x reference)
//
#include <hip/hip_runtime.h>
#include <hip/hip_bf16.h>
#include <cstdint>
#include <cstddef>

// ---------------- types / constants ----------------
typedef _Float16 half8 __attribute__((ext_vector_type(8)));
typedef _Float16 half4 __attribute__((ext_vector_type(4)));
typedef _Float16 half2v __attribute__((ext_vector_type(2)));
typedef float floatx4 __attribute__((ext_vector_type(4)));

#define KIN   2608          // gate input dim
#define KP    2624          // padded to 41*64
#define GH    1024          // gate hidden
#define NOUT  80            // H*P
#define NTOK  8192          // B*L
#define HID   2048

__device__ __forceinline__ void async_copy16(const void* gsrc, void* ldst) {
  __builtin_amdgcn_global_load_lds(
      (const __attribute__((address_space(1))) void*)gsrc,
      (__attribute__((address_space(3))) void*)ldst, 16, 0, 0);
}

// ---------------- kernel 0: convert W1/W2 to fp16 (W1 K-padded) ------------
__global__ __launch_bounds__(256) void convertw(
    const float* __restrict__ W1, const float* __restrict__ W2,
    _Float16* __restrict__ W1p, _Float16* __restrict__ W2p)
{
  int i = blockIdx.x * 256 + threadIdx.x;
  const int total1 = GH * KP;         // 2,686,976
  if (i < total1) {
    int n = i / KP;
    int k = i - n * KP;
    W1p[i] = (k < KIN) ? (_Float16)W1[(size_t)n * KIN + k] : (_Float16)0.f;
  } else {
    int j = i - total1;
    if (j < NOUT * GH) W2p[j] = (_Float16)W2[j];
  }
}

// ---------------- kernel 0b: hidden fp32 -> fp16 into gate rows ------------
__global__ __launch_bounds__(256) void convh(
    const float* __restrict__ hidden, _Float16* __restrict__ gate)
{
  int i = blockIdx.x * 256 + threadIdx.x;   // 2,097,152 threads
  int token = i >> 8;
  int c = i & 255;
  const float4* src = (const float4*)(hidden + (size_t)token * HID + c * 8);
  float4 a = src[0], b = src[1];
  half8 hv;
  hv[0] = (_Float16)a.x; hv[1] = (_Float16)a.y; hv[2] = (_Float16)a.z; hv[3] = (_Float16)a.w;
  hv[4] = (_Float16)b.x; hv[5] = (_Float16)b.y; hv[6] = (_Float16)b.z; hv[7] = (_Float16)b.w;
  *(half8*)(gate + (size_t)token * KP + c * 8) = hv;
}

// ---------------- kernel 1: per-(token,head) stats, no cross-lane ops ------
// 131072 threads; each streams 5 paths x 128 dims, all stats thread-local.
__global__ __launch_bounds__(256) void k1_stats(
    const float* __restrict__ p0, const float* __restrict__ p1,
    const float* __restrict__ p2, const float* __restrict__ p3,
    const float* __restrict__ p4,
    _Float16* __restrict__ gate)
{
  const int gid = blockIdx.x * 256 + threadIdx.x;   // token*16 + h
  const int token = gid >> 4;
  const int h = gid & 15;
  const size_t base = (size_t)gid * 128;
  const float* paths[5] = {p0, p1, p2, p3, p4};

  float s[5], s2[5], sa[5], dt[10];
#pragma unroll
  for (int p = 0; p < 5; ++p) { s[p] = 0.f; s2[p] = 0.f; sa[p] = 0.f; }
#pragma unroll
  for (int i = 0; i < 10; ++i) dt[i] = 0.f;

#pragma unroll 2
  for (int c = 0; c < 16; ++c) {
    float v[5][8];
#pragma unroll
    for (int p = 0; p < 5; ++p) {
      const float4* q = (const float4*)(paths[p] + base + c * 8);
      float4 x0 = q[0], x1 = q[1];
      v[p][0] = x0.x; v[p][1] = x0.y; v[p][2] = x0.z; v[p][3] = x0.w;
      v[p][4] = x1.x; v[p][5] = x1.y; v[p][6] = x1.z; v[p][7] = x1.w;
    }
#pragma unroll
    for (int p = 0; p < 5; ++p) {
#pragma unroll
      for (int e = 0; e < 8; ++e) {
        float x = v[p][e];
        s[p] += x; s2[p] += x * x; sa[p] += fabsf(x);
      }
    }
    int pi = 0;
#pragma unroll
    for (int a = 0; a < 5; ++a)
#pragma unroll
      for (int b = a + 1; b < 5; ++b) {
        float d = 0.f;
#pragma unroll
        for (int e = 0; e < 8; ++e) d += v[a][e] * v[b][e];
        dt[pi++] += d;
      }
  }

  _Float16* gs = gate + (size_t)token * KP;
  // stats: [2048 + h*20 + p*4 + {mean,var,abs_mean,l2}]
  float l2v[5];
#pragma unroll
  for (int p = 0; p < 5; ++p) {
    float mean = s[p] * (1.f / 128.f);
    float var  = s2[p] * (1.f / 128.f) - mean * mean;
    float am   = sa[p] * (1.f / 128.f);
    float l2   = sqrtf(s2[p]);
    l2v[p] = l2;
    half4 st;
    st[0] = (_Float16)mean; st[1] = (_Float16)var;
    st[2] = (_Float16)am;   st[3] = (_Float16)l2;
    *(half4*)(gs + 2048 + h * 20 + p * 4) = st;
  }
  // norms: [2368 + h*5 + p]
#pragma unroll
  for (int p = 0; p < 5; ++p) gs[2368 + h * 5 + p] = (_Float16)l2v[p];
  // pairwise: [2448 + h*10 + pi]
  {
    float pw[10];
    int pi = 0;
#pragma unroll
    for (int a = 0; a < 5; ++a)
#pragma unroll
      for (int b = a + 1; b < 5; ++b) {
        float d2 = s2[a] + s2[b] - 2.f * dt[pi];
        pw[pi] = sqrtf(fmaxf(d2, 0.f));
        ++pi;
      }
#pragma unroll
    for (int i = 0; i < 5; ++i) {
      half2v t; t[0] = (_Float16)pw[2 * i]; t[1] = (_Float16)pw[2 * i + 1];
      *(half2v*)(gs + 2448 + h * 10 + 2 * i) = t;
    }
  }
  // K-padding zeros [2608..2624), one thread per token
  if (h == 0) {
    half8 z = {(_Float16)0.f, (_Float16)0.f, (_Float16)0.f, (_Float16)0.f,
               (_Float16)0.f, (_Float16)0.f, (_Float16)0.f, (_Float16)0.f};
    *(half8*)(gs + 2608) = z;
    *(half8*)(gs + 2616) = z;
  }
}

// ---------------- kernel 2: GEMM1 + bias + exact gelu ----------------------
// C[M=8192, N=1024] = A[M,KP] * W1p[N,KP]^T ; 128x128 tile, BK=64, f16 MFMA
__global__ __launch_bounds__(256) void gemm1(
    const _Float16* __restrict__ A,    // gate [NTOK][KP]
    const _Float16* __restrict__ Bt,   // W1p  [GH][KP]
    const float* __restrict__ b1,
    _Float16* __restrict__ Hm)         // [NTOK][GH]
{
  __shared__ _Float16 As[128 * 64];
  __shared__ _Float16 Bs[128 * 64];
  const int tid  = threadIdx.x;
  const int lane = tid & 63;
  const int wave = tid >> 6;
  const int m0 = blockIdx.x * 128;
  const int n0 = blockIdx.y * 128;
  const int wm = (wave & 1) * 64;
  const int wn = (wave >> 1) * 64;

  floatx4 acc[4][4];
#pragma unroll
  for (int i = 0; i < 4; ++i)
#pragma unroll
    for (int k = 0; k < 4; ++k) acc[i][k] = (floatx4){0.f, 0.f, 0.f, 0.f};

  for (int kt = 0; kt < KP / 64; ++kt) {
    __syncthreads();
    const int kbase = kt * 64;
#pragma unroll
    for (int r = 0; r < 4; ++r) {
      int chunk = r * 256 + tid;        // 0..1023, 16B chunks
      int row = chunk >> 3;             // 0..127
      int kk  = (chunk & 7) * 8;        // fp16 offset in BK
      const _Float16* ga = A  + (size_t)(m0 + row) * KP + kbase + kk;
      const _Float16* gb = Bt + (size_t)(n0 + row) * KP + kbase + kk;
      // wave-uniform LDS base; HW scatters lane i at base + i*16B
      async_copy16(ga, &As[0] + (r * 2048 + wave * 512));
      async_copy16(gb, &Bs[0] + (r * 2048 + wave * 512));
    }
    __syncthreads();
#pragma unroll
    for (int ks = 0; ks < 2; ++ks) {
      half8 af[4], bf[4];
#pragma unroll
      for (int i = 0; i < 4; ++i) {
        int ar = wm + i * 16 + (lane & 15);
        af[i] = *(const half8*)&As[ar * 64 + ks * 32 + (lane >> 4) * 8];
        int br = wn + i * 16 + (lane & 15);
        bf[i] = *(const half8*)&Bs[br * 64 + ks * 32 + (lane >> 4) * 8];
      }
#pragma unroll
      for (int mi = 0; mi < 4; ++mi)
#pragma unroll
        for (int ni = 0; ni < 4; ++ni)
          acc[mi][ni] = __builtin_amdgcn_mfma_f32_16x16x32_f16(af[mi], bf[ni], acc[mi][ni], 0, 0, 0);
    }
  }
  // epilogue: bias + exact gelu -> fp16
#pragma unroll
  for (int mi = 0; mi < 4; ++mi) {
#pragma unroll
    for (int ni = 0; ni < 4; ++ni) {
      int col = n0 + wn + ni * 16 + (lane & 15);
      float bias = b1[col];
#pragma unroll
      for (int r = 0; r < 4; ++r) {
        int row = m0 + wm + mi * 16 + (lane >> 4) * 4 + r;
        float x = acc[mi][ni][r] + bias;
        float g = 0.5f * x * (1.f + erff(x * 0.70710678118654752f));
        Hm[(size_t)row * GH + col] = (_Float16)g;
      }
    }
  }
}

// ---------------- kernel 3: GEMM2 (logits = H * W2^T + b2) -----------------
__global__ __launch_bounds__(256) void gemm2(
    const _Float16* __restrict__ Hm, const _Float16* __restrict__ W2p,
    const float* __restrict__ b2, float* __restrict__ logits)
{
  const int lane = threadIdx.x & 63;
  const int wave = threadIdx.x >> 6;
  const int m0 = blockIdx.x * 64 + wave * 16;
  const int mrow = m0 + (lane & 15);
  const int koff = (lane >> 4) * 8;
  floatx4 acc[5];
#pragma unroll
  for (int i = 0; i < 5; ++i) acc[i] = (floatx4){0.f, 0.f, 0.f, 0.f};
  for (int k0 = 0; k0 < GH; k0 += 32) {
    half8 af = *(const half8*)&Hm[(size_t)mrow * GH + k0 + koff];
#pragma unroll
    for (int ni = 0; ni < 5; ++ni) {
      half8 bf = *(const half8*)&W2p[(size_t)(ni * 16 + (lane & 15)) * GH + k0 + koff];
      acc[ni] = __builtin_amdgcn_mfma_f32_16x16x32_f16(af, bf, acc[ni], 0, 0, 0);
    }
  }
#pragma unroll
  for (int ni = 0; ni < 5; ++ni) {
    int col = ni * 16 + (lane & 15);
    float bias = b2[col];
#pragma unroll
    for (int r = 0; r < 4; ++r) {
      int row = m0 + (lane >> 4) * 4 + r;
      logits[(size_t)row * NOUT + col] = acc[ni][r] + bias;
    }
  }
}

// ---------------- kernel 4: softmax / clip / renorm ------------------------
__global__ __launch_bounds__(256) void softmaxk(
    const float* __restrict__ logits, const float* __restrict__ log_temp,
    float* __restrict__ probs)
{
  int id = blockIdx.x * 256 + threadIdx.x;   // 8192*16 tasks
  int t = id >> 4;
  int h = id & 15;
  float it = __expf(-log_temp[h]);
  const float* lp = logits + (size_t)t * NOUT + h * 5;
  float x[5];
  float m = -1e30f;
#pragma unroll
  for (int p = 0; p < 5; ++p) { x[p] = lp[p] * it; m = fmaxf(m, x[p]); }
  float ssum = 0.f;
#pragma unroll
  for (int p = 0; p < 5; ++p) { x[p] = __expf(x[p] - m); ssum += x[p]; }
  float inv = 1.f / ssum;
  float c = 0.f;
#pragma unroll
  for (int p = 0; p < 5; ++p) { x[p] = fmaxf(x[p] * inv, 0.02f); c += x[p]; }
  float inv2 = 1.f / c;
  float* pp = probs + (size_t)t * NOUT + h * 5;
#pragma unroll
  for (int p = 0; p < 5; ++p) pp[p] = x[p] * inv2;
}

// ---------------- kernel 5: weighted combine + reg_loss --------------------
__global__ __launch_bounds__(256) void k5_combine(
    const float* __restrict__ p0, const float* __restrict__ p1,
    const float* __restrict__ p2, const float* __restrict__ p3,
    const float* __restrict__ p4,
    const float* __restrict__ probs, float* __restrict__ out)
{
  size_t i4 = (size_t)blockIdx.x * 256 + threadIdx.x;  // float4 index, 4,194,304 total
  int token = (int)(i4 >> 9);
  int rem = (int)(i4 & 511);
  int h = rem >> 5;
  const float* pb = probs + (size_t)token * NOUT + h * 5;
  float w0 = pb[0], w1 = pb[1], w2 = pb[2], w3 = pb[3], w4 = pb[4];
  size_t off = i4 * 4;
  float4 a0 = *(const float4*)(p0 + off);
  float4 a1 = *(const float4*)(p1 + off);
  float4 a2 = *(const float4*)(p2 + off);
  float4 a3 = *(const float4*)(p3 + off);
  float4 a4 = *(const float4*)(p4 + off);
  float4 r;
  r.x = a0.x * w0 + a1.x * w1 + a2.x * w2 + a3.x * w3 + a4.x * w4;
  r.y = a0.y * w0 + a1.y * w1 + a2.y * w2 + a3.y * w3 + a4.y * w4;
  r.z = a0.z * w0 + a1.z * w1 + a2.z * w2 + a3.z * w3 + a4.z * w4;
  r.w = a0.w * w0 + a1.w * w1 + a2.w * w2 + a3.w * w3 + a4.w * w4;
  *(float4*)(out + off) = r;
  if (i4 == 0) out[(size_t)NTOK * 2048] = 0.f;   // reg_loss
}

// ---------------- launch ----------------------------------------------------
extern "C" void kernel_launch(void* const* d_in, const int* in_sizes, int n_in,
                              void* d_out, int out_size, void* d_ws, size_t ws_size,
                              hipStream_t stream) {
  const float* hidden  = (const float*)d_in[0];
  const float* p0      = (const float*)d_in[1];
  const float* p1      = (const float*)d_in[2];
  const float* p2      = (const float*)d_in[3];
  const float* p3      = (const float*)d_in[4];
  const float* p4      = (const float*)d_in[5];
  const float* W1      = (const float*)d_in[6];
  const float* b1      = (const float*)d_in[7];
  const float* W2      = (const float*)d_in[8];
  const float* b2      = (const float*)d_in[9];
  const float* logtemp = (const float*)d_in[10];
  float* out = (float*)d_out;

  char* ws = (char*)d_ws;
  _Float16* gate = (_Float16*)(ws);                         // 8192*2624*2 = 42,991,616
  _Float16* W1p  = (_Float16*)(ws + 42991616);              // 1024*2624*2 =  5,373,952
  _Float16* W2p  = (_Float16*)(ws + 48365568);              // 80*1024*2   =    163,840
  _Float16* Hm   = (_Float16*)(ws + 48529408);              // 8192*1024*2 = 16,777,216
  float*    logits = (float*)(ws + 65306624);               // 8192*80*4   =  2,621,440
  float*    probs  = (float*)(ws + 67928064);               // 8192*80*4   =  2,621,440

  convertw<<<10816, 256, 0, stream>>>(W1, W2, W1p, W2p);
  convh<<<8192, 256, 0, stream>>>(hidden, gate);
  k1_stats<<<512, 256, 0, stream>>>(p0, p1, p2, p3, p4, gate);
  gemm1<<<dim3(NTOK / 128, GH / 128), 256, 0, stream>>>(gate, W1p, b1, Hm);
  gemm2<<<NTOK / 64, 256, 0, stream>>>(Hm, W2p, b2, logits);
  softmaxk<<<(NTOK * 16) / 256, 256, 0, stream>>>(logits, logtemp, probs);
  k5_combine<<<(NTOK * 2048 / 4) / 256, 256, 0, stream>>>(p0, p1, p2, p3, p4, probs, out);
}

// Round 3
// 564.450 us; speedup vs baseline: 1.0764x; 1.0764x over previous
//
#include <hip/hip_runtime.h>
#include <hip/hip_bf16.h>
#include <cstdint>
#include <cstddef>

// ---------------- types / constants ----------------
typedef _Float16 half8 __attribute__((ext_vector_type(8)));
typedef _Float16 half4 __attribute__((ext_vector_type(4)));
typedef _Float16 half2v __attribute__((ext_vector_type(2)));
typedef float floatx4 __attribute__((ext_vector_type(4)));

#define KIN   2608          // gate input dim
#define KP    2624          // padded to 41*64
#define GH    1024          // gate hidden
#define NOUT  80            // H*P
#define NTOK  8192          // B*L
#define HID   2048

__device__ __forceinline__ void async_copy16(const void* gsrc, void* ldst) {
  __builtin_amdgcn_global_load_lds(
      (const __attribute__((address_space(1))) void*)gsrc,
      (__attribute__((address_space(3))) void*)ldst, 16, 0, 0);
}

// ---------------- kernel 0: convert W1/W2 to fp16 (W1 K-padded) ------------
__global__ __launch_bounds__(256) void convertw(
    const float* __restrict__ W1, const float* __restrict__ W2,
    _Float16* __restrict__ W1p, _Float16* __restrict__ W2p)
{
  int i = blockIdx.x * 256 + threadIdx.x;
  const int total1 = GH * KP;         // 2,686,976
  if (i < total1) {
    int n = i / KP;
    int k = i - n * KP;
    W1p[i] = (k < KIN) ? (_Float16)W1[(size_t)n * KIN + k] : (_Float16)0.f;
  } else {
    int j = i - total1;
    if (j < NOUT * GH) W2p[j] = (_Float16)W2[j];
  }
}

// ---------------- kernel 1: fused stats + hidden->fp16 ---------------------
// one wave per token; 4 lanes per head (quad), interleaved float4 chunks.
// After stats, the wave converts its token's 2048 hidden floats to fp16.
__global__ __launch_bounds__(256) void k1_fused(
    const float* __restrict__ hidden,
    const float* __restrict__ p0, const float* __restrict__ p1,
    const float* __restrict__ p2, const float* __restrict__ p3,
    const float* __restrict__ p4,
    _Float16* __restrict__ gate)
{
  const int wave = threadIdx.x >> 6;
  const int lane = threadIdx.x & 63;
  const int token = blockIdx.x * 4 + wave;
  const int h = lane >> 2;       // head 0..15
  const int sub = lane & 3;      // quad lane
  const float* paths[5] = {p0, p1, p2, p3, p4};
  const size_t hb = ((size_t)token * 16 + h) * 128;

  float s[5], s2[5], sa[5], dt[10];
#pragma unroll
  for (int p = 0; p < 5; ++p) { s[p] = 0.f; s2[p] = 0.f; sa[p] = 0.f; }
#pragma unroll
  for (int i = 0; i < 10; ++i) dt[i] = 0.f;

#pragma unroll
  for (int j = 0; j < 8; ++j) {
    const int chunk = sub + j * 4;          // float4 chunk 0..31, interleaved
    float v[5][4];
#pragma unroll
    for (int p = 0; p < 5; ++p) {
      float4 x = *(const float4*)(paths[p] + hb + chunk * 4);
      v[p][0] = x.x; v[p][1] = x.y; v[p][2] = x.z; v[p][3] = x.w;
    }
#pragma unroll
    for (int p = 0; p < 5; ++p) {
#pragma unroll
      for (int e = 0; e < 4; ++e) {
        float x = v[p][e];
        s[p] += x; s2[p] += x * x; sa[p] += fabsf(x);
      }
    }
    int pi = 0;
#pragma unroll
    for (int a = 0; a < 5; ++a)
#pragma unroll
      for (int b = a + 1; b < 5; ++b) {
        float d = 0.f;
#pragma unroll
        for (int e = 0; e < 4; ++e) d += v[a][e] * v[b][e];
        dt[pi++] += d;
      }
  }

  // butterfly reduce across the 4-lane quad (all lanes end with totals)
#pragma unroll
  for (int p = 0; p < 5; ++p) {
    s[p]  += __shfl_xor(s[p], 1, 4);  s[p]  += __shfl_xor(s[p], 2, 4);
    s2[p] += __shfl_xor(s2[p], 1, 4); s2[p] += __shfl_xor(s2[p], 2, 4);
    sa[p] += __shfl_xor(sa[p], 1, 4); sa[p] += __shfl_xor(sa[p], 2, 4);
  }
#pragma unroll
  for (int i = 0; i < 10; ++i) {
    dt[i] += __shfl_xor(dt[i], 1, 4); dt[i] += __shfl_xor(dt[i], 2, 4);
  }

  _Float16* gs = gate + (size_t)token * KP;
  // distribute writes across the quad
  if (sub < 2) {
    // stats for p = sub*2, sub*2+1
#pragma unroll
    for (int q = 0; q < 2; ++q) {
      int p = sub * 2 + q;
      float mean = s[p] * (1.f / 128.f);
      float var  = s2[p] * (1.f / 128.f) - mean * mean;
      float am   = sa[p] * (1.f / 128.f);
      float l2   = sqrtf(s2[p]);
      half4 st;
      st[0] = (_Float16)mean; st[1] = (_Float16)var;
      st[2] = (_Float16)am;   st[3] = (_Float16)l2;
      *(half4*)(gs + 2048 + h * 20 + p * 4) = st;
    }
  } else if (sub == 2) {
    // stats for p = 4
    {
      int p = 4;
      float mean = s[p] * (1.f / 128.f);
      float var  = s2[p] * (1.f / 128.f) - mean * mean;
      float am   = sa[p] * (1.f / 128.f);
      float l2   = sqrtf(s2[p]);
      half4 st;
      st[0] = (_Float16)mean; st[1] = (_Float16)var;
      st[2] = (_Float16)am;   st[3] = (_Float16)l2;
      *(half4*)(gs + 2048 + h * 20 + p * 4) = st;
    }
    // norms
#pragma unroll
    for (int p = 0; p < 5; ++p) gs[2368 + h * 5 + p] = (_Float16)sqrtf(s2[p]);
  } else {
    // pairwise distances
    float pw[10];
    int pi = 0;
#pragma unroll
    for (int a = 0; a < 5; ++a)
#pragma unroll
      for (int b = a + 1; b < 5; ++b) {
        float d2 = s2[a] + s2[b] - 2.f * dt[pi];
        pw[pi] = sqrtf(fmaxf(d2, 0.f));
        ++pi;
      }
#pragma unroll
    for (int i = 0; i < 5; ++i) {
      half2v t; t[0] = (_Float16)pw[2 * i]; t[1] = (_Float16)pw[2 * i + 1];
      *(half2v*)(gs + 2448 + h * 10 + 2 * i) = t;
    }
    if (h == 0) {
      half8 z = {(_Float16)0.f, (_Float16)0.f, (_Float16)0.f, (_Float16)0.f,
                 (_Float16)0.f, (_Float16)0.f, (_Float16)0.f, (_Float16)0.f};
      *(half8*)(gs + 2608) = z;
      *(half8*)(gs + 2616) = z;
    }
  }

  // hidden fp32 -> fp16 into gate row (wave covers the whole token)
  const float* hrow = hidden + (size_t)token * HID;
#pragma unroll
  for (int j = 0; j < 4; ++j) {
    int c = lane + 64 * j;                  // chunk of 8 floats, 0..255
    float4 a = *(const float4*)(hrow + c * 8);
    float4 b = *(const float4*)(hrow + c * 8 + 4);
    half8 hv;
    hv[0] = (_Float16)a.x; hv[1] = (_Float16)a.y; hv[2] = (_Float16)a.z; hv[3] = (_Float16)a.w;
    hv[4] = (_Float16)b.x; hv[5] = (_Float16)b.y; hv[6] = (_Float16)b.z; hv[7] = (_Float16)b.w;
    *(half8*)(gs + c * 8) = hv;
  }
}

// ---------------- kernel 2: GEMM1 + bias + exact gelu ----------------------
// C[M=8192, N=1024] = A[M,KP] * W1p[N,KP]^T ; 128x128 tile, BK=64, f16 MFMA
__global__ __launch_bounds__(256) void gemm1(
    const _Float16* __restrict__ A,    // gate [NTOK][KP]
    const _Float16* __restrict__ Bt,   // W1p  [GH][KP]
    const float* __restrict__ b1,
    _Float16* __restrict__ Hm)         // [NTOK][GH]
{
  __shared__ _Float16 As[128 * 64];
  __shared__ _Float16 Bs[128 * 64];
  const int tid  = threadIdx.x;
  const int lane = tid & 63;
  const int wave = tid >> 6;
  const int m0 = blockIdx.x * 128;
  const int n0 = blockIdx.y * 128;
  const int wm = (wave & 1) * 64;
  const int wn = (wave >> 1) * 64;

  floatx4 acc[4][4];
#pragma unroll
  for (int i = 0; i < 4; ++i)
#pragma unroll
    for (int k = 0; k < 4; ++k) acc[i][k] = (floatx4){0.f, 0.f, 0.f, 0.f};

  for (int kt = 0; kt < KP / 64; ++kt) {
    __syncthreads();
    const int kbase = kt * 64;
#pragma unroll
    for (int r = 0; r < 4; ++r) {
      int chunk = r * 256 + tid;        // 0..1023, 16B chunks
      int row = chunk >> 3;             // 0..127
      int kk  = (chunk & 7) * 8;        // fp16 offset in BK
      const _Float16* ga = A  + (size_t)(m0 + row) * KP + kbase + kk;
      const _Float16* gb = Bt + (size_t)(n0 + row) * KP + kbase + kk;
      // wave-uniform LDS base; HW scatters lane i at base + i*16B
      async_copy16(ga, &As[0] + (r * 2048 + wave * 512));
      async_copy16(gb, &Bs[0] + (r * 2048 + wave * 512));
    }
    __syncthreads();
#pragma unroll
    for (int ks = 0; ks < 2; ++ks) {
      half8 af[4], bf[4];
#pragma unroll
      for (int i = 0; i < 4; ++i) {
        int ar = wm + i * 16 + (lane & 15);
        af[i] = *(const half8*)&As[ar * 64 + ks * 32 + (lane >> 4) * 8];
        int br = wn + i * 16 + (lane & 15);
        bf[i] = *(const half8*)&Bs[br * 64 + ks * 32 + (lane >> 4) * 8];
      }
#pragma unroll
      for (int mi = 0; mi < 4; ++mi)
#pragma unroll
        for (int ni = 0; ni < 4; ++ni)
          acc[mi][ni] = __builtin_amdgcn_mfma_f32_16x16x32_f16(af[mi], bf[ni], acc[mi][ni], 0, 0, 0);
    }
  }
  // epilogue: bias + exact gelu -> fp16
#pragma unroll
  for (int mi = 0; mi < 4; ++mi) {
#pragma unroll
    for (int ni = 0; ni < 4; ++ni) {
      int col = n0 + wn + ni * 16 + (lane & 15);
      float bias = b1[col];
#pragma unroll
      for (int r = 0; r < 4; ++r) {
        int row = m0 + wm + mi * 16 + (lane >> 4) * 4 + r;
        float x = acc[mi][ni][r] + bias;
        float g = 0.5f * x * (1.f + erff(x * 0.70710678118654752f));
        Hm[(size_t)row * GH + col] = (_Float16)g;
      }
    }
  }
}

// ---------------- kernel 3: GEMM2 (logits = H * W2^T + b2) -----------------
__global__ __launch_bounds__(256) void gemm2(
    const _Float16* __restrict__ Hm, const _Float16* __restrict__ W2p,
    const float* __restrict__ b2, float* __restrict__ logits)
{
  const int lane = threadIdx.x & 63;
  const int wave = threadIdx.x >> 6;
  const int m0 = blockIdx.x * 64 + wave * 16;
  const int mrow = m0 + (lane & 15);
  const int koff = (lane >> 4) * 8;
  floatx4 acc[5];
#pragma unroll
  for (int i = 0; i < 5; ++i) acc[i] = (floatx4){0.f, 0.f, 0.f, 0.f};
  for (int k0 = 0; k0 < GH; k0 += 32) {
    half8 af = *(const half8*)&Hm[(size_t)mrow * GH + k0 + koff];
#pragma unroll
    for (int ni = 0; ni < 5; ++ni) {
      half8 bf = *(const half8*)&W2p[(size_t)(ni * 16 + (lane & 15)) * GH + k0 + koff];
      acc[ni] = __builtin_amdgcn_mfma_f32_16x16x32_f16(af, bf, acc[ni], 0, 0, 0);
    }
  }
#pragma unroll
  for (int ni = 0; ni < 5; ++ni) {
    int col = ni * 16 + (lane & 15);
    float bias = b2[col];
#pragma unroll
    for (int r = 0; r < 4; ++r) {
      int row = m0 + (lane >> 4) * 4 + r;
      logits[(size_t)row * NOUT + col] = acc[ni][r] + bias;
    }
  }
}

// ---------------- kernel 4: softmax / clip / renorm ------------------------
__global__ __launch_bounds__(256) void softmaxk(
    const float* __restrict__ logits, const float* __restrict__ log_temp,
    float* __restrict__ probs)
{
  int id = blockIdx.x * 256 + threadIdx.x;   // 8192*16 tasks
  int t = id >> 4;
  int h = id & 15;
  float it = __expf(-log_temp[h]);
  const float* lp = logits + (size_t)t * NOUT + h * 5;
  float x[5];
  float m = -1e30f;
#pragma unroll
  for (int p = 0; p < 5; ++p) { x[p] = lp[p] * it; m = fmaxf(m, x[p]); }
  float ssum = 0.f;
#pragma unroll
  for (int p = 0; p < 5; ++p) { x[p] = __expf(x[p] - m); ssum += x[p]; }
  float inv = 1.f / ssum;
  float c = 0.f;
#pragma unroll
  for (int p = 0; p < 5; ++p) { x[p] = fmaxf(x[p] * inv, 0.02f); c += x[p]; }
  float inv2 = 1.f / c;
  float* pp = probs + (size_t)t * NOUT + h * 5;
#pragma unroll
  for (int p = 0; p < 5; ++p) pp[p] = x[p] * inv2;
}

// ---------------- kernel 5: weighted combine + reg_loss --------------------
__global__ __launch_bounds__(256) void k5_combine(
    const float* __restrict__ p0, const float* __restrict__ p1,
    const float* __restrict__ p2, const float* __restrict__ p3,
    const float* __restrict__ p4,
    const float* __restrict__ probs, float* __restrict__ out)
{
  size_t i4 = (size_t)blockIdx.x * 256 + threadIdx.x;  // float4 index, 4,194,304 total
  int token = (int)(i4 >> 9);
  int rem = (int)(i4 & 511);
  int h = rem >> 5;
  const float* pb = probs + (size_t)token * NOUT + h * 5;
  float w0 = pb[0], w1 = pb[1], w2 = pb[2], w3 = pb[3], w4 = pb[4];
  size_t off = i4 * 4;
  float4 a0 = *(const float4*)(p0 + off);
  float4 a1 = *(const float4*)(p1 + off);
  float4 a2 = *(const float4*)(p2 + off);
  float4 a3 = *(const float4*)(p3 + off);
  float4 a4 = *(const float4*)(p4 + off);
  float4 r;
  r.x = a0.x * w0 + a1.x * w1 + a2.x * w2 + a3.x * w3 + a4.x * w4;
  r.y = a0.y * w0 + a1.y * w1 + a2.y * w2 + a3.y * w3 + a4.y * w4;
  r.z = a0.z * w0 + a1.z * w1 + a2.z * w2 + a3.z * w3 + a4.z * w4;
  r.w = a0.w * w0 + a1.w * w1 + a2.w * w2 + a3.w * w3 + a4.w * w4;
  *(float4*)(out + off) = r;
  if (i4 == 0) out[(size_t)NTOK * 2048] = 0.f;   // reg_loss
}

// ---------------- launch ----------------------------------------------------
extern "C" void kernel_launch(void* const* d_in, const int* in_sizes, int n_in,
                              void* d_out, int out_size, void* d_ws, size_t ws_size,
                              hipStream_t stream) {
  const float* hidden  = (const float*)d_in[0];
  const float* p0      = (const float*)d_in[1];
  const float* p1      = (const float*)d_in[2];
  const float* p2      = (const float*)d_in[3];
  const float* p3      = (const float*)d_in[4];
  const float* p4      = (const float*)d_in[5];
  const float* W1      = (const float*)d_in[6];
  const float* b1      = (const float*)d_in[7];
  const float* W2      = (const float*)d_in[8];
  const float* b2      = (const float*)d_in[9];
  const float* logtemp = (const float*)d_in[10];
  float* out = (float*)d_out;

  char* ws = (char*)d_ws;
  _Float16* gate = (_Float16*)(ws);                         // 8192*2624*2 = 42,991,616
  _Float16* W1p  = (_Float16*)(ws + 42991616);              // 1024*2624*2 =  5,373,952
  _Float16* W2p  = (_Float16*)(ws + 48365568);              // 80*1024*2   =    163,840
  _Float16* Hm   = (_Float16*)(ws + 48529408);              // 8192*1024*2 = 16,777,216
  float*    logits = (float*)(ws + 65306624);               // 8192*80*4   =  2,621,440
  float*    probs  = (float*)(ws + 67928064);               // 8192*80*4   =  2,621,440

  convertw<<<10816, 256, 0, stream>>>(W1, W2, W1p, W2p);
  k1_fused<<<2048, 256, 0, stream>>>(hidden, p0, p1, p2, p3, p4, gate);
  gemm1<<<dim3(NTOK / 128, GH / 128), 256, 0, stream>>>(gate, W1p, b1, Hm);
  gemm2<<<NTOK / 64, 256, 0, stream>>>(Hm, W2p, b2, logits);
  softmaxk<<<(NTOK * 16) / 256, 256, 0, stream>>>(logits, logtemp, probs);
  k5_combine<<<(NTOK * 2048 / 4) / 256, 256, 0, stream>>>(p0, p1, p2, p3, p4, probs, out);
}

// Round 4
// 559.370 us; speedup vs baseline: 1.0862x; 1.0091x over previous
//
#include <hip/hip_runtime.h>
#include <hip/hip_bf16.h>
#include <cstdint>
#include <cstddef>

// ---------------- types / constants ----------------
typedef _Float16 half8 __attribute__((ext_vector_type(8)));
typedef _Float16 half4 __attribute__((ext_vector_type(4)));
typedef _Float16 half2v __attribute__((ext_vector_type(2)));
typedef float floatx4 __attribute__((ext_vector_type(4)));

#define KIN   2608          // gate input dim
#define KP    2624          // padded to 41*64
#define GH    1024          // gate hidden
#define NOUT  80            // H*P
#define NTOK  8192          // B*L
#define HID   2048

__device__ __forceinline__ void async_copy16(const void* gsrc, void* ldst) {
  __builtin_amdgcn_global_load_lds(
      (const __attribute__((address_space(1))) void*)gsrc,
      (__attribute__((address_space(3))) void*)ldst, 16, 0, 0);
}

// ---------------- kernel 0: convert W1/W2 to fp16 (W1 K-padded) ------------
__global__ __launch_bounds__(256) void convertw(
    const float* __restrict__ W1, const float* __restrict__ W2,
    _Float16* __restrict__ W1p, _Float16* __restrict__ W2p)
{
  int i = blockIdx.x * 256 + threadIdx.x;
  const int total1 = GH * KP;         // 2,686,976
  if (i < total1) {
    int n = i / KP;
    int k = i - n * KP;
    W1p[i] = (k < KIN) ? (_Float16)W1[(size_t)n * KIN + k] : (_Float16)0.f;
  } else {
    int j = i - total1;
    if (j < NOUT * GH) W2p[j] = (_Float16)W2[j];
  }
}

// ---------------- kernel 1: LDS-staged stats + hidden->fp16 ----------------
// one 128-thread block per token. Stage 5x8KB paths into LDS via async DMA
// (40 x 1KB wave-copies, all in flight), hidden row into regs under the same
// latency shadow, then compute stats from LDS (conflict-free banking).
__global__ __launch_bounds__(128) void k1_staged(
    const float* __restrict__ hidden,
    const float* __restrict__ p0, const float* __restrict__ p1,
    const float* __restrict__ p2, const float* __restrict__ p3,
    const float* __restrict__ p4,
    _Float16* __restrict__ gate)
{
  __shared__ float lds[10240];             // 40 KB: [path][2048 floats]
  const int tid  = threadIdx.x;
  const int wave = tid >> 6;               // 0..1
  const int lane = tid & 63;
  const int token = blockIdx.x;
  const float* paths[5] = {p0, p1, p2, p3, p4};

  // ---- stage: 40 segments of 1KB; wave w takes segments 2r+w ----
#pragma unroll
  for (int r = 0; r < 20; ++r) {
    int i = r * 2 + wave;                  // 0..39
    int p = i >> 3;                        // path
    int s = i & 7;                         // 1KB segment within path block
    const float* src = paths[p] + (size_t)token * 2048 + s * 256 + lane * 4;
    async_copy16(src, (char*)lds + i * 1024);
  }

  // ---- hidden row loads (under staging latency shadow) ----
  float4 hv[4];
  const float* hrow = hidden + (size_t)token * HID;
#pragma unroll
  for (int j = 0; j < 4; ++j)
    hv[j] = *(const float4*)(hrow + (j * 128 + tid) * 4);

  __syncthreads();   // drains vmcnt (async copies + hidden loads)

  _Float16* gs = gate + (size_t)token * KP;

  // ---- hidden fp32 -> fp16 store ----
#pragma unroll
  for (int j = 0; j < 4; ++j) {
    half4 o;
    o[0] = (_Float16)hv[j].x; o[1] = (_Float16)hv[j].y;
    o[2] = (_Float16)hv[j].z; o[3] = (_Float16)hv[j].w;
    *(half4*)(gs + (j * 128 + tid) * 4) = o;
  }
  // K-padding zeros
  if (tid == 0) {
    half8 z = {(_Float16)0.f, (_Float16)0.f, (_Float16)0.f, (_Float16)0.f,
               (_Float16)0.f, (_Float16)0.f, (_Float16)0.f, (_Float16)0.f};
    *(half8*)(gs + 2608) = z;
    *(half8*)(gs + 2616) = z;
  }

  // ---- stats from LDS: 8 lanes per head, 16 elems per lane ----
  const int idx  = wave * 64 + lane;       // 0..127
  const int head = idx >> 3;
  const int sub  = idx & 7;

  float s[5], s2[5], sa[5], dt[10];
#pragma unroll
  for (int p = 0; p < 5; ++p) { s[p] = 0.f; s2[p] = 0.f; sa[p] = 0.f; }
#pragma unroll
  for (int i = 0; i < 10; ++i) dt[i] = 0.f;

#pragma unroll
  for (int j = 0; j < 4; ++j) {
    float v[5][4];
#pragma unroll
    for (int p = 0; p < 5; ++p) {
      // float index: p*2048 + head*128 + j*32 + sub*4 -> bank-group == sub
      const float4 x = *(const float4*)&lds[p * 2048 + head * 128 + j * 32 + sub * 4];
      v[p][0] = x.x; v[p][1] = x.y; v[p][2] = x.z; v[p][3] = x.w;
    }
#pragma unroll
    for (int p = 0; p < 5; ++p) {
#pragma unroll
      for (int e = 0; e < 4; ++e) {
        float x = v[p][e];
        s[p] += x; s2[p] += x * x; sa[p] += fabsf(x);
      }
    }
    int pi = 0;
#pragma unroll
    for (int a = 0; a < 5; ++a)
#pragma unroll
      for (int b = a + 1; b < 5; ++b) {
        float d = 0.f;
#pragma unroll
        for (int e = 0; e < 4; ++e) d += v[a][e] * v[b][e];
        dt[pi++] += d;
      }
  }

  // butterfly reduce across the 8-lane group
#pragma unroll
  for (int p = 0; p < 5; ++p) {
    s[p]  += __shfl_xor(s[p], 1, 8);  s[p]  += __shfl_xor(s[p], 2, 8);  s[p]  += __shfl_xor(s[p], 4, 8);
    s2[p] += __shfl_xor(s2[p], 1, 8); s2[p] += __shfl_xor(s2[p], 2, 8); s2[p] += __shfl_xor(s2[p], 4, 8);
    sa[p] += __shfl_xor(sa[p], 1, 8); sa[p] += __shfl_xor(sa[p], 2, 8); sa[p] += __shfl_xor(sa[p], 4, 8);
  }
#pragma unroll
  for (int i = 0; i < 10; ++i) {
    dt[i] += __shfl_xor(dt[i], 1, 8); dt[i] += __shfl_xor(dt[i], 2, 8); dt[i] += __shfl_xor(dt[i], 4, 8);
  }

  // ---- distribute writes across the 8-lane group ----
  if (sub < 5) {
    int p = sub;
    float mean = s[p] * (1.f / 128.f);
    float var  = s2[p] * (1.f / 128.f) - mean * mean;
    float am   = sa[p] * (1.f / 128.f);
    float l2   = sqrtf(s2[p]);
    half4 st;
    st[0] = (_Float16)mean; st[1] = (_Float16)var;
    st[2] = (_Float16)am;   st[3] = (_Float16)l2;
    *(half4*)(gs + 2048 + head * 20 + p * 4) = st;
  } else if (sub == 5) {
#pragma unroll
    for (int p = 0; p < 5; ++p) gs[2368 + head * 5 + p] = (_Float16)sqrtf(s2[p]);
  } else {
    // pairwise distances: sub==6 -> pi 0..4, sub==7 -> pi 5..9
    int lo = (sub == 6) ? 0 : 5;
    int pi = 0;
#pragma unroll
    for (int a = 0; a < 5; ++a)
#pragma unroll
      for (int b = a + 1; b < 5; ++b) {
        if (pi >= lo && pi < lo + 5) {
          float d2 = s2[a] + s2[b] - 2.f * dt[pi];
          gs[2448 + head * 10 + pi] = (_Float16)sqrtf(fmaxf(d2, 0.f));
        }
        ++pi;
      }
  }
}

// ---------------- kernel 2: GEMM1 + bias + exact gelu ----------------------
// C[M=8192, N=1024] = A[M,KP] * W1p[N,KP]^T ; 128x128 tile, BK=64, f16 MFMA
__global__ __launch_bounds__(256) void gemm1(
    const _Float16* __restrict__ A,    // gate [NTOK][KP]
    const _Float16* __restrict__ Bt,   // W1p  [GH][KP]
    const float* __restrict__ b1,
    _Float16* __restrict__ Hm)         // [NTOK][GH]
{
  __shared__ _Float16 As[128 * 64];
  __shared__ _Float16 Bs[128 * 64];
  const int tid  = threadIdx.x;
  const int lane = tid & 63;
  const int wave = tid >> 6;
  const int m0 = blockIdx.x * 128;
  const int n0 = blockIdx.y * 128;
  const int wm = (wave & 1) * 64;
  const int wn = (wave >> 1) * 64;

  floatx4 acc[4][4];
#pragma unroll
  for (int i = 0; i < 4; ++i)
#pragma unroll
    for (int k = 0; k < 4; ++k) acc[i][k] = (floatx4){0.f, 0.f, 0.f, 0.f};

  for (int kt = 0; kt < KP / 64; ++kt) {
    __syncthreads();
    const int kbase = kt * 64;
#pragma unroll
    for (int r = 0; r < 4; ++r) {
      int chunk = r * 256 + tid;        // 0..1023, 16B chunks
      int row = chunk >> 3;             // 0..127
      int kk  = (chunk & 7) * 8;        // fp16 offset in BK
      const _Float16* ga = A  + (size_t)(m0 + row) * KP + kbase + kk;
      const _Float16* gb = Bt + (size_t)(n0 + row) * KP + kbase + kk;
      // wave-uniform LDS base; HW scatters lane i at base + i*16B
      async_copy16(ga, &As[0] + (r * 2048 + wave * 512));
      async_copy16(gb, &Bs[0] + (r * 2048 + wave * 512));
    }
    __syncthreads();
#pragma unroll
    for (int ks = 0; ks < 2; ++ks) {
      half8 af[4], bf[4];
#pragma unroll
      for (int i = 0; i < 4; ++i) {
        int ar = wm + i * 16 + (lane & 15);
        af[i] = *(const half8*)&As[ar * 64 + ks * 32 + (lane >> 4) * 8];
        int br = wn + i * 16 + (lane & 15);
        bf[i] = *(const half8*)&Bs[br * 64 + ks * 32 + (lane >> 4) * 8];
      }
#pragma unroll
      for (int mi = 0; mi < 4; ++mi)
#pragma unroll
        for (int ni = 0; ni < 4; ++ni)
          acc[mi][ni] = __builtin_amdgcn_mfma_f32_16x16x32_f16(af[mi], bf[ni], acc[mi][ni], 0, 0, 0);
    }
  }
  // epilogue: bias + exact gelu -> fp16
#pragma unroll
  for (int mi = 0; mi < 4; ++mi) {
#pragma unroll
    for (int ni = 0; ni < 4; ++ni) {
      int col = n0 + wn + ni * 16 + (lane & 15);
      float bias = b1[col];
#pragma unroll
      for (int r = 0; r < 4; ++r) {
        int row = m0 + wm + mi * 16 + (lane >> 4) * 4 + r;
        float x = acc[mi][ni][r] + bias;
        float g = 0.5f * x * (1.f + erff(x * 0.70710678118654752f));
        Hm[(size_t)row * GH + col] = (_Float16)g;
      }
    }
  }
}

// ---------------- kernel 3: GEMM2 (logits = H * W2^T + b2) -----------------
__global__ __launch_bounds__(256) void gemm2(
    const _Float16* __restrict__ Hm, const _Float16* __restrict__ W2p,
    const float* __restrict__ b2, float* __restrict__ logits)
{
  const int lane = threadIdx.x & 63;
  const int wave = threadIdx.x >> 6;
  const int m0 = blockIdx.x * 64 + wave * 16;
  const int mrow = m0 + (lane & 15);
  const int koff = (lane >> 4) * 8;
  floatx4 acc[5];
#pragma unroll
  for (int i = 0; i < 5; ++i) acc[i] = (floatx4){0.f, 0.f, 0.f, 0.f};
  for (int k0 = 0; k0 < GH; k0 += 32) {
    half8 af = *(const half8*)&Hm[(size_t)mrow * GH + k0 + koff];
#pragma unroll
    for (int ni = 0; ni < 5; ++ni) {
      half8 bf = *(const half8*)&W2p[(size_t)(ni * 16 + (lane & 15)) * GH + k0 + koff];
      acc[ni] = __builtin_amdgcn_mfma_f32_16x16x32_f16(af, bf, acc[ni], 0, 0, 0);
    }
  }
#pragma unroll
  for (int ni = 0; ni < 5; ++ni) {
    int col = ni * 16 + (lane & 15);
    float bias = b2[col];
#pragma unroll
    for (int r = 0; r < 4; ++r) {
      int row = m0 + (lane >> 4) * 4 + r;
      logits[(size_t)row * NOUT + col] = acc[ni][r] + bias;
    }
  }
}

// ---------------- kernel 4: softmax / clip / renorm ------------------------
__global__ __launch_bounds__(256) void softmaxk(
    const float* __restrict__ logits, const float* __restrict__ log_temp,
    float* __restrict__ probs)
{
  int id = blockIdx.x * 256 + threadIdx.x;   // 8192*16 tasks
  int t = id >> 4;
  int h = id & 15;
  float it = __expf(-log_temp[h]);
  const float* lp = logits + (size_t)t * NOUT + h * 5;
  float x[5];
  float m = -1e30f;
#pragma unroll
  for (int p = 0; p < 5; ++p) { x[p] = lp[p] * it; m = fmaxf(m, x[p]); }
  float ssum = 0.f;
#pragma unroll
  for (int p = 0; p < 5; ++p) { x[p] = __expf(x[p] - m); ssum += x[p]; }
  float inv = 1.f / ssum;
  float c = 0.f;
#pragma unroll
  for (int p = 0; p < 5; ++p) { x[p] = fmaxf(x[p] * inv, 0.02f); c += x[p]; }
  float inv2 = 1.f / c;
  float* pp = probs + (size_t)t * NOUT + h * 5;
#pragma unroll
  for (int p = 0; p < 5; ++p) pp[p] = x[p] * inv2;
}

// ---------------- kernel 5: weighted combine + reg_loss --------------------
__global__ __launch_bounds__(256) void k5_combine(
    const float* __restrict__ p0, const float* __restrict__ p1,
    const float* __restrict__ p2, const float* __restrict__ p3,
    const float* __restrict__ p4,
    const float* __restrict__ probs, float* __restrict__ out)
{
  size_t i4 = (size_t)blockIdx.x * 256 + threadIdx.x;  // float4 index, 4,194,304 total
  int token = (int)(i4 >> 9);
  int rem = (int)(i4 & 511);
  int h = rem >> 5;
  const float* pb = probs + (size_t)token * NOUT + h * 5;
  float w0 = pb[0], w1 = pb[1], w2 = pb[2], w3 = pb[3], w4 = pb[4];
  size_t off = i4 * 4;
  float4 a0 = *(const float4*)(p0 + off);
  float4 a1 = *(const float4*)(p1 + off);
  float4 a2 = *(const float4*)(p2 + off);
  float4 a3 = *(const float4*)(p3 + off);
  float4 a4 = *(const float4*)(p4 + off);
  float4 r;
  r.x = a0.x * w0 + a1.x * w1 + a2.x * w2 + a3.x * w3 + a4.x * w4;
  r.y = a0.y * w0 + a1.y * w1 + a2.y * w2 + a3.y * w3 + a4.y * w4;
  r.z = a0.z * w0 + a1.z * w1 + a2.z * w2 + a3.z * w3 + a4.z * w4;
  r.w = a0.w * w0 + a1.w * w1 + a2.w * w2 + a3.w * w3 + a4.w * w4;
  *(float4*)(out + off) = r;
  if (i4 == 0) out[(size_t)NTOK * 2048] = 0.f;   // reg_loss
}

// ---------------- launch ----------------------------------------------------
extern "C" void kernel_launch(void* const* d_in, const int* in_sizes, int n_in,
                              void* d_out, int out_size, void* d_ws, size_t ws_size,
                              hipStream_t stream) {
  const float* hidden  = (const float*)d_in[0];
  const float* p0      = (const float*)d_in[1];
  const float* p1      = (const float*)d_in[2];
  const float* p2      = (const float*)d_in[3];
  const float* p3      = (const float*)d_in[4];
  const float* p4      = (const float*)d_in[5];
  const float* W1      = (const float*)d_in[6];
  const float* b1      = (const float*)d_in[7];
  const float* W2      = (const float*)d_in[8];
  const float* b2      = (const float*)d_in[9];
  const float* logtemp = (const float*)d_in[10];
  float* out = (float*)d_out;

  char* ws = (char*)d_ws;
  _Float16* gate = (_Float16*)(ws);                         // 8192*2624*2 = 42,991,616
  _Float16* W1p  = (_Float16*)(ws + 42991616);              // 1024*2624*2 =  5,373,952
  _Float16* W2p  = (_Float16*)(ws + 48365568);              // 80*1024*2   =    163,840
  _Float16* Hm   = (_Float16*)(ws + 48529408);              // 8192*1024*2 = 16,777,216
  float*    logits = (float*)(ws + 65306624);               // 8192*80*4   =  2,621,440
  float*    probs  = (float*)(ws + 67928064);               // 8192*80*4   =  2,621,440

  convertw<<<10816, 256, 0, stream>>>(W1, W2, W1p, W2p);
  k1_staged<<<NTOK, 128, 0, stream>>>(hidden, p0, p1, p2, p3, p4, gate);
  gemm1<<<dim3(NTOK / 128, GH / 128), 256, 0, stream>>>(gate, W1p, b1, Hm);
  gemm2<<<NTOK / 64, 256, 0, stream>>>(Hm, W2p, b2, logits);
  softmaxk<<<(NTOK * 16) / 256, 256, 0, stream>>>(logits, logtemp, probs);
  k5_combine<<<(NTOK * 2048 / 4) / 256, 256, 0, stream>>>(p0, p1, p2, p3, p4, probs, out);
}